// Round 13
// baseline (687.932 us; speedup 1.0000x reference)
//
#include <hip/hip_runtime.h>
#include <hip/hip_bf16.h>

// Problem constants (fixed by reference setup_inputs)
#define M_TOK 16384   // B*S = 8*2048
#define DK    4096    // D_IN
#define DN    4096    // D_OUT
#define NE    8       // experts
#define NR    16      // lora rank
#define ERC   128     // E*R
#define RAC   160     // padded router+A columns (8 + 128 + 24 pad)
#define NT_MAIN 128   // base K-tiles of 32
#define NT_ALL  132   // + 4 expert K-tiles

typedef __attribute__((ext_vector_type(8))) short bfrag;   // 8 bf16 (4 VGPRs)
typedef __attribute__((ext_vector_type(4))) float f32x4;   // MFMA acc

__device__ __forceinline__ unsigned short f2bf(float f) {
  unsigned u = __builtin_bit_cast(unsigned, f);
  unsigned rounding = 0x7FFFu + ((u >> 16) & 1u);
  u += rounding;
  return (unsigned short)(u >> 16);
}

__device__ __forceinline__ void load_lds16(const void* g, void* l) {
  __builtin_amdgcn_global_load_lds(
      (__attribute__((address_space(1))) void*)(g),
      (__attribute__((address_space(3))) void*)(l), 16, 0, 0);
}

// ---------- conversion kernels ----------
__global__ void k_cvt(const float* __restrict__ in, unsigned short* __restrict__ out, long n4) {
  long i = (long)blockIdx.x * blockDim.x + threadIdx.x;
  long stride = (long)gridDim.x * blockDim.x;
  for (; i < n4; i += stride) {
    float4 v = reinterpret_cast<const float4*>(in)[i];
    ushort4 o;
    o.x = f2bf(v.x); o.y = f2bf(v.y); o.z = f2bf(v.z); o.w = f2bf(v.w);
    reinterpret_cast<ushort4*>(out)[i] = o;
  }
}

// RA[c][k], c in [0,160): c<8 -> W_router[c][k]; 8<=c<136 -> lora_A[e][k][r]; pad 0
__global__ void k_build_ra(const float* __restrict__ Wr, const float* __restrict__ lA,
                           unsigned short* __restrict__ RA) {
  int idx = blockIdx.x * 256 + threadIdx.x;
  if (idx >= RAC * DK) return;
  int c = idx >> 12;          // /4096
  int k = idx & (DK - 1);
  float v = 0.f;
  if (c < NE) {
    v = Wr[c * DK + k];
  } else if (c < NE + ERC) {
    int er = c - NE;
    int e = er >> 4, r = er & 15;
    v = lA[((long)e * DK + k) * NR + r];
  }
  RA[idx] = f2bf(v);
}

// BT[n][kp] = lora_B[kp/16][kp%16][n]  -> [DN][128] bf16
__global__ void k_build_bt(const float* __restrict__ lB, unsigned short* __restrict__ BT) {
  int idx = blockIdx.x * 256 + threadIdx.x;
  if (idx >= DN * ERC) return;
  int n = idx >> 7;
  int kp = idx & 127;
  BT[idx] = f2bf(lB[(long)kp * DN + n]);
}

// ---------- fused small kernel (R9 proven) -----------------------------------
__global__ __launch_bounds__(256, 2)
void k_small_fused(const float* __restrict__ x, const unsigned short* __restrict__ RA,
                   unsigned short* __restrict__ Xb, const float* __restrict__ b_router,
                   unsigned short* __restrict__ Gout) {
  __shared__ unsigned short At[64 * 64];
  __shared__ unsigned short Bt[RAC * 64];
  __shared__ float Hl[64][160];
  __shared__ float Wl[64][NE];
  int m0 = blockIdx.x * 64;
  int tid = threadIdx.x;
  int lane = tid & 63, wid = tid >> 6;
  int wr = wid >> 1, wc = wid & 1;      // 2x2 waves; wave tile 32 x 80
  int l16 = lane & 15, lhi = lane >> 4;
  f32x4 acc[2][5] = {};
  int row = tid >> 2, c16 = (tid & 3) * 16;
  int byteoff = tid * 16;
  for (int k0 = 0; k0 < DK; k0 += 64) {
    const float* xs = x + (long)(m0 + row) * DK + k0 + c16;
    float4 v0 = *(const float4*)(xs);
    float4 v1 = *(const float4*)(xs + 4);
    float4 v2 = *(const float4*)(xs + 8);
    float4 v3 = *(const float4*)(xs + 12);
    bfrag lo, hi;
    lo[0] = (short)f2bf(v0.x); lo[1] = (short)f2bf(v0.y);
    lo[2] = (short)f2bf(v0.z); lo[3] = (short)f2bf(v0.w);
    lo[4] = (short)f2bf(v1.x); lo[5] = (short)f2bf(v1.y);
    lo[6] = (short)f2bf(v1.z); lo[7] = (short)f2bf(v1.w);
    hi[0] = (short)f2bf(v2.x); hi[1] = (short)f2bf(v2.y);
    hi[2] = (short)f2bf(v2.z); hi[3] = (short)f2bf(v2.w);
    hi[4] = (short)f2bf(v3.x); hi[5] = (short)f2bf(v3.y);
    hi[6] = (short)f2bf(v3.z); hi[7] = (short)f2bf(v3.w);
    unsigned short* xb = Xb + (long)(m0 + row) * DK + k0 + c16;
    *(bfrag*)xb = lo;
    *(bfrag*)(xb + 8) = hi;
    *(bfrag*)&At[row * 64 + c16] = lo;
    *(bfrag*)&At[row * 64 + c16 + 8] = hi;
#pragma unroll
    for (int r = 0; r < 5; r++) {
      int off = r * 4096 + byteoff;
      int rrow = off >> 7, colb = off & 127;
      load_lds16((const char*)RA + ((long)rrow * DK + k0) * 2 + colb, (char*)Bt + off);
    }
    __syncthreads();
#pragma unroll
    for (int kk = 0; kk < 2; kk++) {
      bfrag a[2], b[5];
#pragma unroll
      for (int m = 0; m < 2; m++)
        a[m] = *(const bfrag*)&At[(wr * 32 + m * 16 + l16) * 64 + kk * 32 + lhi * 8];
#pragma unroll
      for (int n = 0; n < 5; n++)
        b[n] = *(const bfrag*)&Bt[(wc * 80 + n * 16 + l16) * 64 + kk * 32 + lhi * 8];
#pragma unroll
      for (int m = 0; m < 2; m++)
#pragma unroll
        for (int n = 0; n < 5; n++)
          acc[m][n] = __builtin_amdgcn_mfma_f32_16x16x32_bf16(a[m], b[n], acc[m][n], 0, 0, 0);
    }
    __syncthreads();
  }
#pragma unroll
  for (int m = 0; m < 2; m++)
#pragma unroll
    for (int n = 0; n < 5; n++) {
      int col = wc * 80 + n * 16 + l16;
      int trow = wr * 32 + m * 16 + lhi * 4;
#pragma unroll
      for (int j = 0; j < 4; j++)
        Hl[trow + j][col] = acc[m][n][j];
    }
  __syncthreads();
  if (tid < 64) {
    float z[NE], zs[NE];
#pragma unroll
    for (int e = 0; e < NE; e++) { z[e] = Hl[tid][e] + b_router[e]; zs[e] = z[e]; }
#pragma unroll
    for (int i = 1; i < NE; i++) {
      float key = zs[i];
      int j = i - 1;
      while (j >= 0 && zs[j] < key) { zs[j + 1] = zs[j]; j--; }
      zs[j + 1] = key;
    }
    float cums[NE];
    float cum = 0.f;
#pragma unroll
    for (int j = 0; j < NE; j++) { cum += zs[j]; cums[j] = cum; }
    int kz = 0;
#pragma unroll
    for (int j = 0; j < NE; j++)
      if (1.f + (float)(j + 1) * zs[j] > cums[j]) kz = j + 1;
    float tau = (cums[kz - 1] - 1.f) / (float)kz;
#pragma unroll
    for (int e = 0; e < NE; e++)
      Wl[tid][e] = fmaxf(z[e] - tau, 0.f);
  }
  __syncthreads();
  for (int idx = tid; idx < 64 * ERC; idx += 256) {
    int tk = idx >> 7, er = idx & 127;
    Gout[(long)(m0 + tk) * ERC + er] = f2bf(Wl[tk][er >> 4] * Hl[tk][NE + er]);
  }
}

// ---------- main GEMM: 256x256, BK=32, 3-SLOT RING, ONE BARRIER PER TILE -----
// out = Xb @ Wb^T + bias + G @ BT^T, fused as 128 + 4 K-tiles of 32.
// R12 forensics: with any pre-MFMA barrier, all 8 waves issue read bursts in
// lockstep -> LDS FIFO completes everyone's operands ~simultaneously -> LDS
// (2304 cyc/tile) and MFMA (2484) strictly alternate (sum = measured 4790).
// This kernel has NO intra-tile barrier: tile body = {reads(12 b128) ->
// 32 MFMA (compiler counted lgkm waits interleave reads under MFMA) ->
// stage(t+2) -> vmcnt(4)+barrier}. Waves desynchronize between boundaries.
// Hazard ledger (3 slots, slot(t)=t%3; stage targets slot(t+2) != slot(t),
// != slot(t+1) -> no intra-tile WAR exists):
//  - RAW: boundary(t) vmcnt(4) keeps only stage(t+2)'s 4 loads in flight ->
//    stage(t+1) drained; barrier -> visible to all. Tile t+1 reads safe.
//  - WAR: stage(t+2) overwrites slot(t-1), last read during tile t-1. A wave
//    issues stage(t+2) only after boundary(t-1)'s COLLECTIVE barrier, which
//    each wave passes only after its tile-(t-1) MFMAs (whose counted waits
//    retired those reads). Safe.
//  - ds_reads precede glds in program order per tile; boundary asm ("memory")
//    blocks cross-tile reordering of memory ops.
// Mappings/swizzle verbatim from R5 (ref-checked, 0 bank conflicts).
struct KtArgs {
  const unsigned short *pXA0, *pXA1, *pWB0, *pWB1, *pGA0, *pGA1, *pTB0, *pTB1;
  int soffA0, soffA1, soffB0, soffB1;   // element offsets within a ring slot
  int wr, wc, l16, swslot;              // swslot in shorts
};

template<bool STG, int VMB>
__device__ __forceinline__ void ktile_body(int t, int s, int su, unsigned short* lds,
                                           const KtArgs& A, f32x4 (&acc)[8][4]) {
  unsigned short* L = lds + s * 16384;
  bfrag b[4], a[8];
  // reads: b first, then a (first MFMA cluster needs a[0],b[*]); the compiler
  // inserts counted lgkmcnt per operand, so the read tail drains under MFMA.
#pragma unroll
  for (int n = 0; n < 4; n++)
    b[n] = *(const bfrag*)&L[8192 + (A.wc * 64 + n * 16 + A.l16) * 32 + A.swslot];
#pragma unroll
  for (int m = 0; m < 8; m++)
    a[m] = *(const bfrag*)&L[(A.wr * 128 + m * 16 + A.l16) * 32 + A.swslot];
  __builtin_amdgcn_s_setprio(1);
#pragma unroll
  for (int m = 0; m < 8; m++)
#pragma unroll
    for (int n = 0; n < 4; n++)
      acc[m][n] = __builtin_amdgcn_mfma_f32_16x16x32_bf16(a[m], b[n], acc[m][n], 0, 0, 0);
  __builtin_amdgcn_s_setprio(0);
  if constexpr (STG) {
    int u = t + 2;
    unsigned short* d = lds + su * 16384;
    if (u < NT_MAIN) {
      load_lds16(A.pXA0 + (long)u * 32, d + A.soffA0);
      load_lds16(A.pXA1 + (long)u * 32, d + A.soffA1);
      load_lds16(A.pWB0 + (long)u * 32, d + A.soffB0);
      load_lds16(A.pWB1 + (long)u * 32, d + A.soffB1);
    } else {
      long v = u - NT_MAIN;
      load_lds16(A.pGA0 + v * 32, d + A.soffA0);
      load_lds16(A.pGA1 + v * 32, d + A.soffA1);
      load_lds16(A.pTB0 + v * 32, d + A.soffB0);
      load_lds16(A.pTB1 + v * 32, d + A.soffB1);
    }
  }
  if constexpr (VMB == 4)      asm volatile("s_waitcnt vmcnt(4)\n\ts_barrier" ::: "memory");
  else if constexpr (VMB == 0) asm volatile("s_waitcnt vmcnt(0)\n\ts_barrier" ::: "memory");
  // VMB < 0: last tile, no boundary
}

__global__ __launch_bounds__(512, 2)
void k_gemm_main(const unsigned short* __restrict__ X, const unsigned short* __restrict__ W,
                 const unsigned short* __restrict__ G, const unsigned short* __restrict__ BT,
                 const float* __restrict__ bias, float* __restrict__ out) {
  // 3 ring slots x (A[256][32] + B[256][32]) bf16 = 3 x 32 KiB = 96 KiB
  __shared__ unsigned short lds[3 * 16384];
  int bid = blockIdx.x;
  // XCD-aware swizzle: 1024 workgroups, 8 XCDs -> contiguous chunks of 128
  int swz = (bid & 7) * 128 + (bid >> 3);
  int bm = swz >> 4, bn = swz & 15;
  int m0 = bm * 256, n0 = bn * 256;
  int tid = threadIdx.x;
  int lane = tid & 63, wid = tid >> 6;

  KtArgs A;
  A.wr = wid >> 2; A.wc = wid & 3;      // 2x4 waves; wave tile 128 x 64
  A.l16 = lane & 15;
  int lhi = lane >> 4;
  A.swslot = (lhi ^ ((A.l16 >> 1) & 3)) * 8;      // read-side swizzle (shorts)
  int r0 = tid >> 2;
  int c8 = (((tid & 3) ^ ((tid >> 3) & 3)) * 8);  // swizzled source column (shorts)
  A.pXA0 = X + (long)(m0 + r0) * DK + c8;
  A.pXA1 = X + (long)(m0 + 128 + r0) * DK + c8;
  A.pWB0 = W + (long)(n0 + r0) * DK + c8;
  A.pWB1 = W + (long)(n0 + 128 + r0) * DK + c8;
  A.pGA0 = G + (long)(m0 + r0) * ERC + c8;
  A.pGA1 = G + (long)(m0 + 128 + r0) * ERC + c8;
  A.pTB0 = BT + (long)(n0 + r0) * ERC + c8;
  A.pTB1 = BT + (long)(n0 + 128 + r0) * ERC + c8;
  A.soffA0 = tid * 8;
  A.soffA1 = 4096 + tid * 8;
  A.soffB0 = 8192 + tid * 8;
  A.soffB1 = 12288 + tid * 8;

  f32x4 acc[8][4] = {};

  // prologue: stage tile 0 -> slot 0, tile 1 -> slot 1 (base path).
  // vmcnt(4) keeps tile 1's 4 loads in flight; tile 0 drained -> certified.
#pragma unroll
  for (int u = 0; u < 2; u++) {
    unsigned short* d = lds + u * 16384;
    load_lds16(A.pXA0 + (long)u * 32, d + A.soffA0);
    load_lds16(A.pXA1 + (long)u * 32, d + A.soffA1);
    load_lds16(A.pWB0 + (long)u * 32, d + A.soffB0);
    load_lds16(A.pWB1 + (long)u * 32, d + A.soffB1);
  }
  asm volatile("s_waitcnt vmcnt(4)\n\ts_barrier" ::: "memory");

  int s = 0;
  for (int t = 0; t < 130; t++) {
    int su = (s >= 1) ? s - 1 : 2;      // (s+2) % 3
    ktile_body<true, 4>(t, s, su, lds, A, acc);
    s = (s == 2) ? 0 : s + 1;
  }
  ktile_body<false, 0>(130, s, 0, lds, A, acc);
  s = (s == 2) ? 0 : s + 1;
  ktile_body<false, -1>(131, s, 0, lds, A, acc);

  // epilogue: bias + f32 store
#pragma unroll
  for (int n = 0; n < 4; n++) {
    int col = n0 + A.wc * 64 + n * 16 + A.l16;
    float bv = bias[col];
#pragma unroll
    for (int m = 0; m < 8; m++) {
      int row = m0 + A.wr * 128 + m * 16 + lhi * 4;
#pragma unroll
      for (int j = 0; j < 4; j++)
        out[(long)(row + j) * DN + col] = acc[m][n][j] + bv;
    }
  }
}

extern "C" void kernel_launch(void* const* d_in, const int* in_sizes, int n_in,
                              void* d_out, int out_size, void* d_ws, size_t ws_size,
                              hipStream_t stream) {
  const float* x        = (const float*)d_in[0];
  const float* W_base   = (const float*)d_in[1];
  const float* b_base   = (const float*)d_in[2];
  const float* W_router = (const float*)d_in[3];
  const float* b_router = (const float*)d_in[4];
  const float* lora_A   = (const float*)d_in[5];
  const float* lora_B   = (const float*)d_in[6];
  float* out = (float*)d_out;

  char* ws = (char*)d_ws;
  unsigned short* Xb = (unsigned short*)ws;                       // 134217728 B
  unsigned short* Wb = (unsigned short*)(ws + 134217728L);        // 33554432 B
  unsigned short* RA = (unsigned short*)(ws + 167772160L);        // 1310720 B
  unsigned short* BT = (unsigned short*)(ws + 169082880L);        // 1048576 B
  unsigned short* G  = (unsigned short*)(ws + 180617216L);        // 4194304 B

  hipLaunchKernelGGL(k_cvt, dim3(2048), dim3(256), 0, stream, W_base, Wb, (long)DN * DK / 4);
  hipLaunchKernelGGL(k_build_ra, dim3((RAC * DK + 255) / 256), dim3(256), 0, stream,
                     W_router, lora_A, RA);
  hipLaunchKernelGGL(k_build_bt, dim3((DN * ERC + 255) / 256), dim3(256), 0, stream, lora_B, BT);
  // fused: x->bf16 (writes Xb) + router logits/h GEMM + sparsemax + G
  hipLaunchKernelGGL(k_small_fused, dim3(M_TOK / 64), dim3(256), 0, stream,
                     x, RA, Xb, b_router, G);
  // main fused GEMM (3-slot ring, one barrier per K-tile)
  hipLaunchKernelGGL(k_gemm_main, dim3((M_TOK / 256) * (DN / 256)), dim3(512), 0, stream,
                     Xb, Wb, G, BT, b_base, out);
}